// Round 5
// baseline (403.012 us; speedup 1.0000x reference)
//
#include <hip/hip_runtime.h>
#include <math.h>

#define N_NODES 100000
#define E_EDGES 1600000
#define F_IN 32
#define HID 16
#define NC 10
#define SCAN_BLK 1024            // elements per scan block (256 threads * 4)
#define SCAN_NB ((N_NODES + SCAN_BLK - 1) / SCAN_BLK)   // 98
#define SRC_BITS 17
#define SRC_MASK ((1u << SRC_BITS) - 1u)
#define VQ_SCALE 32767.0f

// bf16 pack (RNE) of two floats into one uint: low16 = lo, high16 = hi
__device__ __forceinline__ unsigned int bf16pair(float lo, float hi) {
    unsigned int ulo = __float_as_uint(lo), uhi = __float_as_uint(hi);
    ulo += 0x7fffu + ((ulo >> 16) & 1u);
    uhi += 0x7fffu + ((uhi >> 16) & 1u);
    return (ulo >> 16) | (uhi & 0xffff0000u);
}

// ---------------- Kernel: per-node projections for layer 1 ----------------
// y[n] = 16 uints, pair o = (x@W1[0])[o] , (x@W1[1])[o] in bf16. r1 = x@root1+b1 (f32).
__global__ __launch_bounds__(256) void node_l1(
    const float* __restrict__ x, const float* __restrict__ W1,
    const float* __restrict__ root1, const float* __restrict__ b1,
    unsigned int* __restrict__ y, float* __restrict__ r1)
{
    __shared__ float sW0[F_IN * HID], sW1[F_IN * HID], sR[F_IN * HID], sB[HID];
    for (int i = threadIdx.x; i < F_IN * HID; i += 256) {
        sW0[i] = W1[i];
        sW1[i] = W1[F_IN * HID + i];
        sR[i]  = root1[i];
    }
    if (threadIdx.x < HID) sB[threadIdx.x] = b1[threadIdx.x];
    __syncthreads();

    int n = blockIdx.x * 256 + threadIdx.x;
    if (n >= N_NODES) return;

    float xr[F_IN];
    const float4* xp = (const float4*)(x + (size_t)n * F_IN);
    #pragma unroll
    for (int i = 0; i < F_IN / 4; i++) {
        float4 t = xp[i];
        xr[i*4+0] = t.x; xr[i*4+1] = t.y; xr[i*4+2] = t.z; xr[i*4+3] = t.w;
    }

    float a0[HID], a1[HID], ar[HID];
    #pragma unroll
    for (int o = 0; o < HID; o++) { a0[o] = 0.f; a1[o] = 0.f; ar[o] = sB[o]; }
    for (int i = 0; i < F_IN; i++) {
        float xi = xr[i];
        #pragma unroll
        for (int o = 0; o < HID; o++) {
            a0[o] += xi * sW0[i * HID + o];
            a1[o] += xi * sW1[i * HID + o];
            ar[o] += xi * sR[i * HID + o];
        }
    }
    unsigned int* py = y + (size_t)n * 16;
    float* pr = r1 + (size_t)n * HID;
    #pragma unroll
    for (int o = 0; o < HID; o++) {
        py[o] = bf16pair(a0[o], a1[o]);
        pr[o] = ar[o];
    }
}

// ---------------- Sort step 1: histogram over dst (also = deg) ----------------
__global__ __launch_bounds__(256) void k_hist(const int* __restrict__ ei, int* __restrict__ hist)
{
    int e = blockIdx.x * 256 + threadIdx.x;
    if (e >= E_EDGES) return;
    atomicAdd(&hist[ei[E_EDGES + e]], 1);
}

// ---- Sort step 2a: per-block scan. Block b covers [b*1024, b*1024+1024). ----
__global__ __launch_bounds__(256) void scan_a(const int* __restrict__ hist,
                                              int* __restrict__ start,
                                              int* __restrict__ bsum)
{
    __shared__ int lds[256];
    int t = threadIdx.x;
    int base = blockIdx.x * SCAN_BLK + t * 4;
    int v0 = 0, v1 = 0, v2 = 0, v3 = 0;
    if (base + 3 < N_NODES) {
        int4 h4 = *(const int4*)(hist + base);
        v0 = h4.x; v1 = h4.y; v2 = h4.z; v3 = h4.w;
    } else {
        if (base + 0 < N_NODES) v0 = hist[base + 0];
        if (base + 1 < N_NODES) v1 = hist[base + 1];
        if (base + 2 < N_NODES) v2 = hist[base + 2];
        if (base + 3 < N_NODES) v3 = hist[base + 3];
    }
    int s = v0 + v1 + v2 + v3;
    lds[t] = s;
    __syncthreads();
    #pragma unroll
    for (int off = 1; off < 256; off <<= 1) {
        int u = (t >= off) ? lds[t - off] : 0;
        __syncthreads();
        lds[t] += u;
        __syncthreads();
    }
    int ex = lds[t] - s;
    if (base + 0 < N_NODES) start[base + 0] = ex;
    if (base + 1 < N_NODES) start[base + 1] = ex + v0;
    if (base + 2 < N_NODES) start[base + 2] = ex + v0 + v1;
    if (base + 3 < N_NODES) start[base + 3] = ex + v0 + v1 + v2;
    if (t == 255) bsum[blockIdx.x] = lds[255];
}

// ---- Sort step 2b: scan the 98 block sums. ----
__global__ __launch_bounds__(128) void scan_b(const int* __restrict__ bsum,
                                              int* __restrict__ boff,
                                              int* __restrict__ start)
{
    __shared__ int lds[128];
    int t = threadIdx.x;
    int s = (t < SCAN_NB) ? bsum[t] : 0;
    lds[t] = s;
    __syncthreads();
    #pragma unroll
    for (int off = 1; off < 128; off <<= 1) {
        int u = (t >= off) ? lds[t - off] : 0;
        __syncthreads();
        lds[t] += u;
        __syncthreads();
    }
    if (t < SCAN_NB) boff[t] = lds[t] - s;
    if (t == 127) start[N_NODES] = lds[127];   // total = E
}

// ---- Sort step 2c: add block offsets; mirror into cursor. ----
__global__ __launch_bounds__(256) void scan_c(int* __restrict__ start,
                                              int* __restrict__ cursor,
                                              const int* __restrict__ boff)
{
    int t = threadIdx.x;
    int off = boff[blockIdx.x];
    int base = blockIdx.x * SCAN_BLK + t * 4;
    #pragma unroll
    for (int i = 0; i < 4; i++) {
        int j = base + i;
        if (j < N_NODES) {
            int v = start[j] + off;
            start[j] = v;
            cursor[j] = v;
        }
    }
}

// ---------------- Sort step 3: scatter packed (vq<<17 | src) ----------------
__global__ __launch_bounds__(256) void k_scatter(const int* __restrict__ ei,
                                                 const float* __restrict__ ea,
                                                 int* __restrict__ cursor,
                                                 unsigned int* __restrict__ es)
{
    int e = blockIdx.x * 256 + threadIdx.x;
    if (e >= E_EDGES) return;
    int dst = ei[E_EDGES + e];
    int src = ei[e];
    unsigned int vq = (unsigned int)(ea[e] * VQ_SCALE + 0.5f);
    int pos = atomicAdd(&cursor[dst], 1);
    es[pos] = (vq << SRC_BITS) | (unsigned int)src;
}

// ------- Aggregation layer 1: 16 lanes/node, atomic-free; fused mean+root+elu -------
// In-place: r1h holds r1 on entry, h on exit.
__global__ __launch_bounds__(256) void k_agg1(
    const unsigned int* __restrict__ es, const int* __restrict__ start,
    const int* __restrict__ hist, const unsigned int* __restrict__ y,
    float* __restrict__ r1h)
{
    int idx = blockIdx.x * 256 + threadIdx.x;
    int n = idx >> 4, o = idx & 15;
    if (n >= N_NODES) return;
    int j0 = start[n], j1 = start[n + 1];
    float acc = 0.f;
    for (int j = j0; j < j1; j++) {
        unsigned int p = es[j];
        float v = (float)(p >> SRC_BITS) * (1.0f / VQ_SCALE);
        unsigned int pair = y[(size_t)(p & SRC_MASK) * 16 + o];  // one 64B line/edge
        float a = __uint_as_float(pair << 16);
        float b = __uint_as_float(pair & 0xffff0000u);
        acc += fmaf(v, b - a, a);                      // a*(1-v) + b*v
    }
    float inv = 1.0f / fmaxf((float)hist[n], 1.0f);
    float hv = acc * inv + r1h[(size_t)n * HID + o];
    r1h[(size_t)n * HID + o] = hv > 0.0f ? hv : expm1f(hv);  // elu
}

// ---------------- Layer-2 projections: z (bf16 pairs, padded), r2 ----------------
__global__ __launch_bounds__(256) void node_proj2(
    const float* __restrict__ h,
    const float* __restrict__ W2, const float* __restrict__ root2,
    const float* __restrict__ b2,
    unsigned int* __restrict__ z, float* __restrict__ r2)
{
    __shared__ float sW0[HID * NC], sW1[HID * NC], sR[HID * NC], sB[NC];
    for (int i = threadIdx.x; i < HID * NC; i += 256) {
        sW0[i] = W2[i];
        sW1[i] = W2[HID * NC + i];
        sR[i]  = root2[i];
    }
    if (threadIdx.x < NC) sB[threadIdx.x] = b2[threadIdx.x];
    __syncthreads();

    int n = blockIdx.x * 256 + threadIdx.x;
    if (n >= N_NODES) return;

    float hr[HID];
    const float4* hp = (const float4*)(h + (size_t)n * HID);
    #pragma unroll
    for (int i = 0; i < HID / 4; i++) {
        float4 t = hp[i];
        hr[i*4+0] = t.x; hr[i*4+1] = t.y; hr[i*4+2] = t.z; hr[i*4+3] = t.w;
    }
    float a0[NC], a1[NC], ar[NC];
    #pragma unroll
    for (int c = 0; c < NC; c++) { a0[c] = 0.f; a1[c] = 0.f; ar[c] = sB[c]; }
    for (int i = 0; i < HID; i++) {
        float hi = hr[i];
        #pragma unroll
        for (int c = 0; c < NC; c++) {
            a0[c] += hi * sW0[i * NC + c];
            a1[c] += hi * sW1[i * NC + c];
            ar[c] += hi * sR[i * NC + c];
        }
    }
    unsigned int* pz = z + (size_t)n * 16;
    float* pr = r2 + (size_t)n * NC;
    #pragma unroll
    for (int c = 0; c < NC; c++) {
        pz[c] = bf16pair(a0[c], a1[c]);
        pr[c] = ar[c];
    }
    #pragma unroll
    for (int c = NC; c < 16; c++) pz[c] = 0u;   // keep lanes 10..15 benign
}

// -- Aggregation layer 2: 16 lanes/node; fused mean+root+log_softmax (shfl, width 16) --
__global__ __launch_bounds__(256) void k_agg2(
    const unsigned int* __restrict__ es, const int* __restrict__ start,
    const int* __restrict__ hist, const unsigned int* __restrict__ z,
    const float* __restrict__ r2, float* __restrict__ out)
{
    int idx = blockIdx.x * 256 + threadIdx.x;
    int n = idx >> 4, o = idx & 15;
    if (n >= N_NODES) return;
    int j0 = start[n], j1 = start[n + 1];
    float acc = 0.f;
    for (int j = j0; j < j1; j++) {
        unsigned int p = es[j];
        float v = (float)(p >> SRC_BITS) * (1.0f / VQ_SCALE);
        unsigned int pair = z[(size_t)(p & SRC_MASK) * 16 + o];
        float a = __uint_as_float(pair << 16);
        float b = __uint_as_float(pair & 0xffff0000u);
        acc += fmaf(v, b - a, a);
    }
    float val = -INFINITY;
    if (o < NC) {
        float inv = 1.0f / fmaxf((float)hist[n], 1.0f);
        val = acc * inv + r2[(size_t)n * NC + o];
    }
    float mx = val;
    #pragma unroll
    for (int off = 8; off > 0; off >>= 1) mx = fmaxf(mx, __shfl_xor(mx, off, 16));
    float ex = (o < NC) ? expf(val - mx) : 0.0f;
    float ssum = ex;
    #pragma unroll
    for (int off = 8; off > 0; off >>= 1) ssum += __shfl_xor(ssum, off, 16);
    if (o < NC) out[(size_t)n * NC + o] = val - mx - logf(ssum);
}

extern "C" void kernel_launch(void* const* d_in, const int* in_sizes, int n_in,
                              void* d_out, int out_size, void* d_ws, size_t ws_size,
                              hipStream_t stream) {
    const float* x     = (const float*)d_in[0];
    const int*   ei    = (const int*)d_in[1];     // [2,E] src row then dst row
    const float* ea    = (const float*)d_in[2];   // [E,1]
    const float* W1    = (const float*)d_in[3];   // [2,32,16]
    const float* root1 = (const float*)d_in[4];   // [32,16]
    const float* b1    = (const float*)d_in[5];   // [16]
    const float* W2    = (const float*)d_in[6];   // [2,16,10]
    const float* root2 = (const float*)d_in[7];   // [16,10]
    const float* b2    = (const float*)d_in[8];   // [10]
    float* out = (float*)d_out;

    // Workspace layout (4-byte units).
    char* wsb = (char*)d_ws;
    unsigned int* es     = (unsigned int*)wsb;                          // 1.6M * 4B (packed)
    unsigned int* y      = (unsigned int*)(wsb + (size_t)E_EDGES * 4);  // 1.6M * 4B
    float*        r1h    = (float*)(y + (size_t)N_NODES * 16);          // 1.6M * 4B
    unsigned int* z      = (unsigned int*)(r1h + (size_t)N_NODES * HID);// 1.6M * 4B
    float*        r2     = (float*)(z + (size_t)N_NODES * 16);          // 1.0M * 4B
    int*          hist   = (int*)(r2 + (size_t)N_NODES * NC);           // 100k (zeroed)
    int*          start  = hist + N_NODES;                              // 100k+1
    int*          cursor = start + N_NODES + 1;                         // 100k
    int*          bsum   = cursor + N_NODES;                            // 98
    int*          boff   = bsum + SCAN_NB;                              // 98

    hipMemsetAsync(hist, 0, (size_t)N_NODES * sizeof(int), stream);

    int nodeGrid = (N_NODES + 255) / 256;
    int edgeGrid = (E_EDGES + 255) / 256;
    int aggGrid  = (N_NODES * 16 + 255) / 256;

    node_l1  <<<nodeGrid, 256, 0, stream>>>(x, W1, root1, b1, y, r1h);
    k_hist   <<<edgeGrid, 256, 0, stream>>>(ei, hist);
    scan_a   <<<SCAN_NB, 256, 0, stream>>>(hist, start, bsum);
    scan_b   <<<1, 128, 0, stream>>>(bsum, boff, start);
    scan_c   <<<SCAN_NB, 256, 0, stream>>>(start, cursor, boff);
    k_scatter<<<edgeGrid, 256, 0, stream>>>(ei, ea, cursor, es);
    k_agg1   <<<aggGrid, 256, 0, stream>>>(es, start, hist, y, r1h);
    node_proj2<<<nodeGrid, 256, 0, stream>>>(r1h, W2, root2, b2, z, r2);
    k_agg2   <<<aggGrid, 256, 0, stream>>>(es, start, hist, z, r2, out);
}

// Round 6
// 286.298 us; speedup vs baseline: 1.4077x; 1.4077x over previous
//
#include <hip/hip_runtime.h>
#include <math.h>

#define N_NODES 100000
#define E_EDGES 1600000
#define F_IN 32
#define HID 16
#define NC 10
#define SRC_BITS 17
#define SRC_MASK ((1u << SRC_BITS) - 1u)
#define VQ_SCALE 32767.0f
#define BUCKET_BITS 10
#define BUCKET_SIZE 1024
#define NBUCKETS ((N_NODES + BUCKET_SIZE - 1) / BUCKET_SIZE)   // 98
#define BLK_E 4096     // edges per block in bucket/hist kernels

// bf16 pack (RNE) of two floats into one uint: low16 = lo, high16 = hi
__device__ __forceinline__ unsigned int bf16pair(float lo, float hi) {
    unsigned int ulo = __float_as_uint(lo), uhi = __float_as_uint(hi);
    ulo += 0x7fffu + ((ulo >> 16) & 1u);
    uhi += 0x7fffu + ((uhi >> 16) & 1u);
    return (ulo >> 16) | (uhi & 0xffff0000u);
}

// ---------------- per-node projections for layer 1 ----------------
__global__ __launch_bounds__(256) void node_l1(
    const float* __restrict__ x, const float* __restrict__ W1,
    const float* __restrict__ root1, const float* __restrict__ b1,
    unsigned int* __restrict__ y, float* __restrict__ r1)
{
    __shared__ float sW0[F_IN * HID], sW1[F_IN * HID], sR[F_IN * HID], sB[HID];
    for (int i = threadIdx.x; i < F_IN * HID; i += 256) {
        sW0[i] = W1[i];
        sW1[i] = W1[F_IN * HID + i];
        sR[i]  = root1[i];
    }
    if (threadIdx.x < HID) sB[threadIdx.x] = b1[threadIdx.x];
    __syncthreads();

    int n = blockIdx.x * 256 + threadIdx.x;
    if (n >= N_NODES) return;

    float xr[F_IN];
    const float4* xp = (const float4*)(x + (size_t)n * F_IN);
    #pragma unroll
    for (int i = 0; i < F_IN / 4; i++) {
        float4 t = xp[i];
        xr[i*4+0] = t.x; xr[i*4+1] = t.y; xr[i*4+2] = t.z; xr[i*4+3] = t.w;
    }

    float a0[HID], a1[HID], ar[HID];
    #pragma unroll
    for (int o = 0; o < HID; o++) { a0[o] = 0.f; a1[o] = 0.f; ar[o] = sB[o]; }
    for (int i = 0; i < F_IN; i++) {
        float xi = xr[i];
        #pragma unroll
        for (int o = 0; o < HID; o++) {
            a0[o] += xi * sW0[i * HID + o];
            a1[o] += xi * sW1[i * HID + o];
            ar[o] += xi * sR[i * HID + o];
        }
    }
    unsigned int* py = y + (size_t)n * 16;
    float* pr = r1 + (size_t)n * HID;
    #pragma unroll
    for (int o = 0; o < HID; o++) {
        py[o] = bf16pair(a0[o], a1[o]);
        pr[o] = ar[o];
    }
}

// ---------------- bucket histogram: 98 bins of dst>>10 ----------------
__global__ __launch_bounds__(256) void k_bhist(const int* __restrict__ ei,
                                               int* __restrict__ gcnt)
{
    __shared__ int h[NBUCKETS];
    for (int i = threadIdx.x; i < NBUCKETS; i += 256) h[i] = 0;
    __syncthreads();
    int e0 = blockIdx.x * BLK_E;
    for (int i = threadIdx.x; i < BLK_E; i += 256) {
        int e = e0 + i;
        if (e < E_EDGES) atomicAdd(&h[ei[E_EDGES + e] >> BUCKET_BITS], 1);
    }
    __syncthreads();
    for (int i = threadIdx.x; i < NBUCKETS; i += 256)
        if (h[i]) atomicAdd(&gcnt[i], h[i]);
}

// ---------------- scan 98 bucket counts -> bucketBase[99] ----------------
__global__ __launch_bounds__(128) void k_bscan(const int* __restrict__ gcnt,
                                               int* __restrict__ bucketBase,
                                               int* __restrict__ start)
{
    __shared__ int lds[128];
    int t = threadIdx.x;
    int s = (t < NBUCKETS) ? gcnt[t] : 0;
    lds[t] = s;
    __syncthreads();
    #pragma unroll
    for (int off = 1; off < 128; off <<= 1) {
        int u = (t >= off) ? lds[t - off] : 0;
        __syncthreads();
        lds[t] += u;
        __syncthreads();
    }
    if (t < NBUCKETS) bucketBase[t] = lds[t] - s;
    if (t == 127) { bucketBase[NBUCKETS] = lds[127]; start[N_NODES] = lds[127]; }
}

// ------- pass A: bin edges into 98 bucket regions of ebuf (L2-resident frontiers) -------
__global__ __launch_bounds__(256) void k_bucket(
    const int* __restrict__ ei, const float* __restrict__ ea,
    const int* __restrict__ bucketBase, int* __restrict__ gcursor,
    int2* __restrict__ ebuf)
{
    __shared__ int cnt[NBUCKETS], base[NBUCKETS], cur[NBUCKETS];
    for (int i = threadIdx.x; i < NBUCKETS; i += 256) cnt[i] = 0;
    __syncthreads();
    int e0 = blockIdx.x * BLK_E;
    for (int i = threadIdx.x; i < BLK_E; i += 256) {
        int e = e0 + i;
        if (e < E_EDGES) atomicAdd(&cnt[ei[E_EDGES + e] >> BUCKET_BITS], 1);
    }
    __syncthreads();
    for (int i = threadIdx.x; i < NBUCKETS; i += 256) {
        int c = cnt[i];
        base[i] = c ? atomicAdd(&gcursor[i], c) : 0;
        cur[i] = 0;
    }
    __syncthreads();
    for (int i = threadIdx.x; i < BLK_E; i += 256) {
        int e = e0 + i;
        if (e >= E_EDGES) continue;
        int dst = ei[E_EDGES + e];          // L2-hit (read in pass 1)
        int b = dst >> BUCKET_BITS;
        int off = atomicAdd(&cur[b], 1);
        unsigned int vq = (unsigned int)(ea[e] * VQ_SCALE + 0.5f);
        unsigned int packed = (vq << SRC_BITS) | (unsigned int)ei[e];
        ebuf[bucketBase[b] + base[b] + off] = make_int2(dst, (int)packed);
    }
}

// ------- pass B: per-bucket exact sort into es + start[] (writes stay in one 64KB window) -------
__global__ __launch_bounds__(1024) void k_bsort(
    const int2* __restrict__ ebuf, const int* __restrict__ bucketBase,
    unsigned int* __restrict__ es, int* __restrict__ start)
{
    __shared__ int hist[BUCKET_SIZE];     // counts -> local exclusive start
    __shared__ int cursor[BUCKET_SIZE];
    __shared__ int scanbuf[BUCKET_SIZE];
    int t = threadIdx.x;
    int b = blockIdx.x;
    int j0 = bucketBase[b], j1 = bucketBase[b + 1];
    hist[t] = 0; cursor[t] = 0;
    __syncthreads();
    for (int j = j0 + t; j < j1; j += 1024)
        atomicAdd(&hist[ebuf[j].x - (b << BUCKET_BITS)], 1);
    __syncthreads();
    int c = hist[t];
    scanbuf[t] = c;
    __syncthreads();
    #pragma unroll
    for (int off = 1; off < BUCKET_SIZE; off <<= 1) {
        int u = (t >= off) ? scanbuf[t - off] : 0;
        __syncthreads();
        scanbuf[t] += u;
        __syncthreads();
    }
    int excl = scanbuf[t] - c;
    hist[t] = excl;                        // reuse as local start
    int node = (b << BUCKET_BITS) + t;
    if (node < N_NODES) start[node] = j0 + excl;
    __syncthreads();
    for (int j = j0 + t; j < j1; j += 1024) {
        int2 p = ebuf[j];
        int local = p.x - (b << BUCKET_BITS);
        int off = atomicAdd(&cursor[local], 1);
        es[j0 + hist[local] + off] = (unsigned int)p.y;
    }
}

// ------- Aggregation layer 1: 16 lanes/node; fused mean+root+elu (deg = segment len) -------
__global__ __launch_bounds__(256) void k_agg1(
    const unsigned int* __restrict__ es, const int* __restrict__ start,
    const unsigned int* __restrict__ y, float* __restrict__ r1h)
{
    int idx = blockIdx.x * 256 + threadIdx.x;
    int n = idx >> 4, o = idx & 15;
    if (n >= N_NODES) return;
    int j0 = start[n], j1 = start[n + 1];
    float acc = 0.f;
    for (int j = j0; j < j1; j++) {
        unsigned int p = es[j];
        float v = (float)(p >> SRC_BITS) * (1.0f / VQ_SCALE);
        unsigned int pair = y[(size_t)(p & SRC_MASK) * 16 + o];  // one 64B line/edge
        float a = __uint_as_float(pair << 16);
        float b = __uint_as_float(pair & 0xffff0000u);
        acc += fmaf(v, b - a, a);
    }
    float inv = 1.0f / fmaxf((float)(j1 - j0), 1.0f);
    float hv = acc * inv + r1h[(size_t)n * HID + o];
    r1h[(size_t)n * HID + o] = hv > 0.0f ? hv : expm1f(hv);  // elu
}

// ---------------- Layer-2 projections: z (bf16 pairs, padded), r2 ----------------
__global__ __launch_bounds__(256) void node_proj2(
    const float* __restrict__ h,
    const float* __restrict__ W2, const float* __restrict__ root2,
    const float* __restrict__ b2,
    unsigned int* __restrict__ z, float* __restrict__ r2)
{
    __shared__ float sW0[HID * NC], sW1[HID * NC], sR[HID * NC], sB[NC];
    for (int i = threadIdx.x; i < HID * NC; i += 256) {
        sW0[i] = W2[i];
        sW1[i] = W2[HID * NC + i];
        sR[i]  = root2[i];
    }
    if (threadIdx.x < NC) sB[threadIdx.x] = b2[threadIdx.x];
    __syncthreads();

    int n = blockIdx.x * 256 + threadIdx.x;
    if (n >= N_NODES) return;

    float hr[HID];
    const float4* hp = (const float4*)(h + (size_t)n * HID);
    #pragma unroll
    for (int i = 0; i < HID / 4; i++) {
        float4 t = hp[i];
        hr[i*4+0] = t.x; hr[i*4+1] = t.y; hr[i*4+2] = t.z; hr[i*4+3] = t.w;
    }
    float a0[NC], a1[NC], ar[NC];
    #pragma unroll
    for (int c = 0; c < NC; c++) { a0[c] = 0.f; a1[c] = 0.f; ar[c] = sB[c]; }
    for (int i = 0; i < HID; i++) {
        float hi = hr[i];
        #pragma unroll
        for (int c = 0; c < NC; c++) {
            a0[c] += hi * sW0[i * NC + c];
            a1[c] += hi * sW1[i * NC + c];
            ar[c] += hi * sR[i * NC + c];
        }
    }
    unsigned int* pz = z + (size_t)n * 16;
    float* pr = r2 + (size_t)n * NC;
    #pragma unroll
    for (int c = 0; c < NC; c++) {
        pz[c] = bf16pair(a0[c], a1[c]);
        pr[c] = ar[c];
    }
    #pragma unroll
    for (int c = NC; c < 16; c++) pz[c] = 0u;
}

// -- Aggregation layer 2: 16 lanes/node; fused mean+root+log_softmax --
__global__ __launch_bounds__(256) void k_agg2(
    const unsigned int* __restrict__ es, const int* __restrict__ start,
    const unsigned int* __restrict__ z,
    const float* __restrict__ r2, float* __restrict__ out)
{
    int idx = blockIdx.x * 256 + threadIdx.x;
    int n = idx >> 4, o = idx & 15;
    if (n >= N_NODES) return;
    int j0 = start[n], j1 = start[n + 1];
    float acc = 0.f;
    for (int j = j0; j < j1; j++) {
        unsigned int p = es[j];
        float v = (float)(p >> SRC_BITS) * (1.0f / VQ_SCALE);
        unsigned int pair = z[(size_t)(p & SRC_MASK) * 16 + o];
        float a = __uint_as_float(pair << 16);
        float b = __uint_as_float(pair & 0xffff0000u);
        acc += fmaf(v, b - a, a);
    }
    float val = -INFINITY;
    if (o < NC) {
        float inv = 1.0f / fmaxf((float)(j1 - j0), 1.0f);
        val = acc * inv + r2[(size_t)n * NC + o];
    }
    float mx = val;
    #pragma unroll
    for (int off = 8; off > 0; off >>= 1) mx = fmaxf(mx, __shfl_xor(mx, off, 16));
    float ex = (o < NC) ? expf(val - mx) : 0.0f;
    float ssum = ex;
    #pragma unroll
    for (int off = 8; off > 0; off >>= 1) ssum += __shfl_xor(ssum, off, 16);
    if (o < NC) out[(size_t)n * NC + o] = val - mx - logf(ssum);
}

extern "C" void kernel_launch(void* const* d_in, const int* in_sizes, int n_in,
                              void* d_out, int out_size, void* d_ws, size_t ws_size,
                              hipStream_t stream) {
    const float* x     = (const float*)d_in[0];
    const int*   ei    = (const int*)d_in[1];     // [2,E] src row then dst row
    const float* ea    = (const float*)d_in[2];   // [E,1]
    const float* W1    = (const float*)d_in[3];
    const float* root1 = (const float*)d_in[4];
    const float* b1    = (const float*)d_in[5];
    const float* W2    = (const float*)d_in[6];
    const float* root2 = (const float*)d_in[7];
    const float* b2    = (const float*)d_in[8];
    float* out = (float*)d_out;

    // Workspace layout (ebuf first: 8B aligned; everything stays 16B aligned).
    char* wsb = (char*)d_ws;
    int2*         ebuf   = (int2*)wsb;                                   // 1.6M * 8B
    unsigned int* es     = (unsigned int*)(wsb + (size_t)E_EDGES * 8);   // 1.6M * 4B
    unsigned int* y      = es + (size_t)E_EDGES;                         // 1.6M * 4B
    float*        r1h    = (float*)(y + (size_t)N_NODES * 16);           // 1.6M * 4B
    unsigned int* z      = (unsigned int*)(r1h + (size_t)N_NODES * HID); // 1.6M * 4B
    float*        r2     = (float*)(z + (size_t)N_NODES * 16);           // 1.0M * 4B
    int*          start  = (int*)(r2 + (size_t)N_NODES * NC);            // N+1
    int*          gcnt   = start + N_NODES + 1;                          // 98 (zeroed)
    int*          gcursor= gcnt + NBUCKETS;                              // 98 (zeroed)
    int*          bucketBase = gcursor + NBUCKETS;                       // 99

    hipMemsetAsync(gcnt, 0, 2 * NBUCKETS * sizeof(int), stream);

    int nodeGrid = (N_NODES + 255) / 256;
    int chunkGrid = (E_EDGES + BLK_E - 1) / BLK_E;   // 391
    int aggGrid  = (N_NODES * 16 + 255) / 256;

    node_l1 <<<nodeGrid, 256, 0, stream>>>(x, W1, root1, b1, y, r1h);
    k_bhist <<<chunkGrid, 256, 0, stream>>>(ei, gcnt);
    k_bscan <<<1, 128, 0, stream>>>(gcnt, bucketBase, start);
    k_bucket<<<chunkGrid, 256, 0, stream>>>(ei, ea, bucketBase, gcursor, ebuf);
    k_bsort <<<NBUCKETS, 1024, 0, stream>>>(ebuf, bucketBase, es, start);
    k_agg1  <<<aggGrid, 256, 0, stream>>>(es, start, y, r1h);
    node_proj2<<<nodeGrid, 256, 0, stream>>>(r1h, W2, root2, b2, z, r2);
    k_agg2  <<<aggGrid, 256, 0, stream>>>(es, start, z, r2, out);
}

// Round 7
// 240.160 us; speedup vs baseline: 1.6781x; 1.1921x over previous
//
#include <hip/hip_runtime.h>
#include <math.h>

#define N_NODES 100000
#define E_EDGES 1600000
#define F_IN 32
#define HID 16
#define NC 10
#define SRC_BITS 17
#define SRC_MASK ((1u << SRC_BITS) - 1u)
#define VQ_SCALE 32767.0f
#define BUCKET_BITS 10
#define BUCKET_SIZE 1024
#define NBUCKETS ((N_NODES + BUCKET_SIZE - 1) / BUCKET_SIZE)   // 98
#define BLK_E 4096     // edges per block in bucket/hist kernels

// bf16 pack (RNE) of two floats into one uint: low16 = lo, high16 = hi
__device__ __forceinline__ unsigned int bf16pair(float lo, float hi) {
    unsigned int ulo = __float_as_uint(lo), uhi = __float_as_uint(hi);
    ulo += 0x7fffu + ((ulo >> 16) & 1u);
    uhi += 0x7fffu + ((uhi >> 16) & 1u);
    return (ulo >> 16) | (uhi & 0xffff0000u);
}

__device__ __forceinline__ float lerp_pair(unsigned int pair, float v) {
    float a = __uint_as_float(pair << 16);
    float b = __uint_as_float(pair & 0xffff0000u);
    return fmaf(v, b - a, a);
}

// ---------------- per-node projections for layer 1 ----------------
__global__ __launch_bounds__(256) void node_l1(
    const float* __restrict__ x, const float* __restrict__ W1,
    const float* __restrict__ root1, const float* __restrict__ b1,
    unsigned int* __restrict__ y, float* __restrict__ r1)
{
    __shared__ float sW0[F_IN * HID], sW1[F_IN * HID], sR[F_IN * HID], sB[HID];
    for (int i = threadIdx.x; i < F_IN * HID; i += 256) {
        sW0[i] = W1[i];
        sW1[i] = W1[F_IN * HID + i];
        sR[i]  = root1[i];
    }
    if (threadIdx.x < HID) sB[threadIdx.x] = b1[threadIdx.x];
    __syncthreads();

    int n = blockIdx.x * 256 + threadIdx.x;
    if (n >= N_NODES) return;

    float xr[F_IN];
    const float4* xp = (const float4*)(x + (size_t)n * F_IN);
    #pragma unroll
    for (int i = 0; i < F_IN / 4; i++) {
        float4 t = xp[i];
        xr[i*4+0] = t.x; xr[i*4+1] = t.y; xr[i*4+2] = t.z; xr[i*4+3] = t.w;
    }

    float a0[HID], a1[HID], ar[HID];
    #pragma unroll
    for (int o = 0; o < HID; o++) { a0[o] = 0.f; a1[o] = 0.f; ar[o] = sB[o]; }
    for (int i = 0; i < F_IN; i++) {
        float xi = xr[i];
        #pragma unroll
        for (int o = 0; o < HID; o++) {
            a0[o] += xi * sW0[i * HID + o];
            a1[o] += xi * sW1[i * HID + o];
            ar[o] += xi * sR[i * HID + o];
        }
    }
    unsigned int* py = y + (size_t)n * 16;
    float* pr = r1 + (size_t)n * HID;
    #pragma unroll
    for (int o = 0; o < HID; o++) {
        py[o] = bf16pair(a0[o], a1[o]);
        pr[o] = ar[o];
    }
}

// ---------------- bucket histogram: 98 bins of dst>>10 ----------------
__global__ __launch_bounds__(256) void k_bhist(const int* __restrict__ ei,
                                               int* __restrict__ gcnt)
{
    __shared__ int h[NBUCKETS];
    for (int i = threadIdx.x; i < NBUCKETS; i += 256) h[i] = 0;
    __syncthreads();
    int e0 = blockIdx.x * BLK_E;
    for (int i = threadIdx.x; i < BLK_E; i += 256) {
        int e = e0 + i;
        if (e < E_EDGES) atomicAdd(&h[ei[E_EDGES + e] >> BUCKET_BITS], 1);
    }
    __syncthreads();
    for (int i = threadIdx.x; i < NBUCKETS; i += 256)
        if (h[i]) atomicAdd(&gcnt[i], h[i]);
}

// ---------------- scan 98 bucket counts -> bucketBase[99] ----------------
__global__ __launch_bounds__(128) void k_bscan(const int* __restrict__ gcnt,
                                               int* __restrict__ bucketBase,
                                               int* __restrict__ start)
{
    __shared__ int lds[128];
    int t = threadIdx.x;
    int s = (t < NBUCKETS) ? gcnt[t] : 0;
    lds[t] = s;
    __syncthreads();
    #pragma unroll
    for (int off = 1; off < 128; off <<= 1) {
        int u = (t >= off) ? lds[t - off] : 0;
        __syncthreads();
        lds[t] += u;
        __syncthreads();
    }
    if (t < NBUCKETS) bucketBase[t] = lds[t] - s;
    if (t == 127) { bucketBase[NBUCKETS] = lds[127]; start[N_NODES] = lds[127]; }
}

// ------- pass A: bin edges into 98 bucket regions of ebuf (L2-resident frontiers) -------
__global__ __launch_bounds__(256) void k_bucket(
    const int* __restrict__ ei, const float* __restrict__ ea,
    const int* __restrict__ bucketBase, int* __restrict__ gcursor,
    int2* __restrict__ ebuf)
{
    __shared__ int cnt[NBUCKETS], base[NBUCKETS], cur[NBUCKETS];
    for (int i = threadIdx.x; i < NBUCKETS; i += 256) cnt[i] = 0;
    __syncthreads();
    int e0 = blockIdx.x * BLK_E;
    for (int i = threadIdx.x; i < BLK_E; i += 256) {
        int e = e0 + i;
        if (e < E_EDGES) atomicAdd(&cnt[ei[E_EDGES + e] >> BUCKET_BITS], 1);
    }
    __syncthreads();
    for (int i = threadIdx.x; i < NBUCKETS; i += 256) {
        int c = cnt[i];
        base[i] = c ? atomicAdd(&gcursor[i], c) : 0;
        cur[i] = 0;
    }
    __syncthreads();
    for (int i = threadIdx.x; i < BLK_E; i += 256) {
        int e = e0 + i;
        if (e >= E_EDGES) continue;
        int dst = ei[E_EDGES + e];          // L2-hit (read in pass 1)
        int b = dst >> BUCKET_BITS;
        int off = atomicAdd(&cur[b], 1);
        unsigned int vq = (unsigned int)(ea[e] * VQ_SCALE + 0.5f);
        unsigned int packed = (vq << SRC_BITS) | (unsigned int)ei[e];
        ebuf[bucketBase[b] + base[b] + off] = make_int2(dst, (int)packed);
    }
}

// ------- pass B: per-bucket exact sort into es + start[] -------
__global__ __launch_bounds__(1024) void k_bsort(
    const int2* __restrict__ ebuf, const int* __restrict__ bucketBase,
    unsigned int* __restrict__ es, int* __restrict__ start)
{
    __shared__ int hist[BUCKET_SIZE];
    __shared__ int cursor[BUCKET_SIZE];
    __shared__ int scanbuf[BUCKET_SIZE];
    int t = threadIdx.x;
    int b = blockIdx.x;
    int j0 = bucketBase[b], j1 = bucketBase[b + 1];
    hist[t] = 0; cursor[t] = 0;
    __syncthreads();
    for (int j = j0 + t; j < j1; j += 1024)
        atomicAdd(&hist[ebuf[j].x - (b << BUCKET_BITS)], 1);
    __syncthreads();
    int c = hist[t];
    scanbuf[t] = c;
    __syncthreads();
    #pragma unroll
    for (int off = 1; off < BUCKET_SIZE; off <<= 1) {
        int u = (t >= off) ? scanbuf[t - off] : 0;
        __syncthreads();
        scanbuf[t] += u;
        __syncthreads();
    }
    int excl = scanbuf[t] - c;
    hist[t] = excl;
    int node = (b << BUCKET_BITS) + t;
    if (node < N_NODES) start[node] = j0 + excl;
    __syncthreads();
    for (int j = j0 + t; j < j1; j += 1024) {
        int2 p = ebuf[j];
        int local = p.x - (b << BUCKET_BITS);
        int off = atomicAdd(&cursor[local], 1);
        es[j0 + hist[local] + off] = (unsigned int)p.y;
    }
}

// ------- Aggregation layer 1: 16 lanes/node; 4-way unrolled gather; fused mean+root+elu -------
__global__ __launch_bounds__(256) void k_agg1(
    const unsigned int* __restrict__ es, const int* __restrict__ start,
    const unsigned int* __restrict__ y, float* __restrict__ r1h)
{
    int idx = blockIdx.x * 256 + threadIdx.x;
    int n = idx >> 4, o = idx & 15;
    if (n >= N_NODES) return;
    int j0 = start[n], j1 = start[n + 1];
    float acc0 = 0.f, acc1 = 0.f, acc2 = 0.f, acc3 = 0.f;
    int j = j0;
    for (; j + 3 < j1; j += 4) {
        unsigned int p0 = es[j], p1 = es[j+1], p2 = es[j+2], p3 = es[j+3];
        unsigned int q0 = y[(size_t)(p0 & SRC_MASK) * 16 + o];
        unsigned int q1 = y[(size_t)(p1 & SRC_MASK) * 16 + o];
        unsigned int q2 = y[(size_t)(p2 & SRC_MASK) * 16 + o];
        unsigned int q3 = y[(size_t)(p3 & SRC_MASK) * 16 + o];
        acc0 += lerp_pair(q0, (float)(p0 >> SRC_BITS) * (1.0f / VQ_SCALE));
        acc1 += lerp_pair(q1, (float)(p1 >> SRC_BITS) * (1.0f / VQ_SCALE));
        acc2 += lerp_pair(q2, (float)(p2 >> SRC_BITS) * (1.0f / VQ_SCALE));
        acc3 += lerp_pair(q3, (float)(p3 >> SRC_BITS) * (1.0f / VQ_SCALE));
    }
    for (; j < j1; j++) {
        unsigned int p = es[j];
        unsigned int q = y[(size_t)(p & SRC_MASK) * 16 + o];
        acc0 += lerp_pair(q, (float)(p >> SRC_BITS) * (1.0f / VQ_SCALE));
    }
    float acc = (acc0 + acc1) + (acc2 + acc3);
    float inv = 1.0f / fmaxf((float)(j1 - j0), 1.0f);
    float hv = acc * inv + r1h[(size_t)n * HID + o];
    r1h[(size_t)n * HID + o] = hv > 0.0f ? hv : expm1f(hv);  // elu
}

// ---------------- Layer-2 projections: z (bf16 pairs, padded), r2 ----------------
__global__ __launch_bounds__(256) void node_proj2(
    const float* __restrict__ h,
    const float* __restrict__ W2, const float* __restrict__ root2,
    const float* __restrict__ b2,
    unsigned int* __restrict__ z, float* __restrict__ r2)
{
    __shared__ float sW0[HID * NC], sW1[HID * NC], sR[HID * NC], sB[NC];
    for (int i = threadIdx.x; i < HID * NC; i += 256) {
        sW0[i] = W2[i];
        sW1[i] = W2[HID * NC + i];
        sR[i]  = root2[i];
    }
    if (threadIdx.x < NC) sB[threadIdx.x] = b2[threadIdx.x];
    __syncthreads();

    int n = blockIdx.x * 256 + threadIdx.x;
    if (n >= N_NODES) return;

    float hr[HID];
    const float4* hp = (const float4*)(h + (size_t)n * HID);
    #pragma unroll
    for (int i = 0; i < HID / 4; i++) {
        float4 t = hp[i];
        hr[i*4+0] = t.x; hr[i*4+1] = t.y; hr[i*4+2] = t.z; hr[i*4+3] = t.w;
    }
    float a0[NC], a1[NC], ar[NC];
    #pragma unroll
    for (int c = 0; c < NC; c++) { a0[c] = 0.f; a1[c] = 0.f; ar[c] = sB[c]; }
    for (int i = 0; i < HID; i++) {
        float hi = hr[i];
        #pragma unroll
        for (int c = 0; c < NC; c++) {
            a0[c] += hi * sW0[i * NC + c];
            a1[c] += hi * sW1[i * NC + c];
            ar[c] += hi * sR[i * NC + c];
        }
    }
    unsigned int* pz = z + (size_t)n * 16;
    float* pr = r2 + (size_t)n * NC;
    #pragma unroll
    for (int c = 0; c < NC; c++) {
        pz[c] = bf16pair(a0[c], a1[c]);
        pr[c] = ar[c];
    }
    #pragma unroll
    for (int c = NC; c < 16; c++) pz[c] = 0u;
}

// -- Aggregation layer 2: 16 lanes/node; 4-way unrolled; fused mean+root+log_softmax --
__global__ __launch_bounds__(256) void k_agg2(
    const unsigned int* __restrict__ es, const int* __restrict__ start,
    const unsigned int* __restrict__ z,
    const float* __restrict__ r2, float* __restrict__ out)
{
    int idx = blockIdx.x * 256 + threadIdx.x;
    int n = idx >> 4, o = idx & 15;
    if (n >= N_NODES) return;
    int j0 = start[n], j1 = start[n + 1];
    float acc0 = 0.f, acc1 = 0.f, acc2 = 0.f, acc3 = 0.f;
    int j = j0;
    for (; j + 3 < j1; j += 4) {
        unsigned int p0 = es[j], p1 = es[j+1], p2 = es[j+2], p3 = es[j+3];
        unsigned int q0 = z[(size_t)(p0 & SRC_MASK) * 16 + o];
        unsigned int q1 = z[(size_t)(p1 & SRC_MASK) * 16 + o];
        unsigned int q2 = z[(size_t)(p2 & SRC_MASK) * 16 + o];
        unsigned int q3 = z[(size_t)(p3 & SRC_MASK) * 16 + o];
        acc0 += lerp_pair(q0, (float)(p0 >> SRC_BITS) * (1.0f / VQ_SCALE));
        acc1 += lerp_pair(q1, (float)(p1 >> SRC_BITS) * (1.0f / VQ_SCALE));
        acc2 += lerp_pair(q2, (float)(p2 >> SRC_BITS) * (1.0f / VQ_SCALE));
        acc3 += lerp_pair(q3, (float)(p3 >> SRC_BITS) * (1.0f / VQ_SCALE));
    }
    for (; j < j1; j++) {
        unsigned int p = es[j];
        unsigned int q = z[(size_t)(p & SRC_MASK) * 16 + o];
        acc0 += lerp_pair(q, (float)(p >> SRC_BITS) * (1.0f / VQ_SCALE));
    }
    float acc = (acc0 + acc1) + (acc2 + acc3);
    float val = -INFINITY;
    if (o < NC) {
        float inv = 1.0f / fmaxf((float)(j1 - j0), 1.0f);
        val = acc * inv + r2[(size_t)n * NC + o];
    }
    float mx = val;
    #pragma unroll
    for (int off = 8; off > 0; off >>= 1) mx = fmaxf(mx, __shfl_xor(mx, off, 16));
    float ex = (o < NC) ? expf(val - mx) : 0.0f;
    float ssum = ex;
    #pragma unroll
    for (int off = 8; off > 0; off >>= 1) ssum += __shfl_xor(ssum, off, 16);
    if (o < NC) out[(size_t)n * NC + o] = val - mx - logf(ssum);
}

extern "C" void kernel_launch(void* const* d_in, const int* in_sizes, int n_in,
                              void* d_out, int out_size, void* d_ws, size_t ws_size,
                              hipStream_t stream) {
    const float* x     = (const float*)d_in[0];
    const int*   ei    = (const int*)d_in[1];     // [2,E] src row then dst row
    const float* ea    = (const float*)d_in[2];   // [E,1]
    const float* W1    = (const float*)d_in[3];
    const float* root1 = (const float*)d_in[4];
    const float* b1    = (const float*)d_in[5];
    const float* W2    = (const float*)d_in[6];
    const float* root2 = (const float*)d_in[7];
    const float* b2    = (const float*)d_in[8];
    float* out = (float*)d_out;

    // Workspace layout (ebuf first: 8B aligned; everything stays 16B aligned).
    char* wsb = (char*)d_ws;
    int2*         ebuf   = (int2*)wsb;                                   // 1.6M * 8B
    unsigned int* es     = (unsigned int*)(wsb + (size_t)E_EDGES * 8);   // 1.6M * 4B
    unsigned int* y      = es + (size_t)E_EDGES;                         // 1.6M * 4B
    float*        r1h    = (float*)(y + (size_t)N_NODES * 16);           // 1.6M * 4B
    unsigned int* z      = (unsigned int*)(r1h + (size_t)N_NODES * HID); // 1.6M * 4B
    float*        r2     = (float*)(z + (size_t)N_NODES * 16);           // 1.0M * 4B
    int*          start  = (int*)(r2 + (size_t)N_NODES * NC);            // N+1
    int*          gcnt   = start + N_NODES + 1;                          // 98 (zeroed)
    int*          gcursor= gcnt + NBUCKETS;                              // 98 (zeroed)
    int*          bucketBase = gcursor + NBUCKETS;                       // 99

    hipMemsetAsync(gcnt, 0, 2 * NBUCKETS * sizeof(int), stream);

    int nodeGrid = (N_NODES + 255) / 256;
    int chunkGrid = (E_EDGES + BLK_E - 1) / BLK_E;   // 391
    int aggGrid  = (N_NODES * 16 + 255) / 256;

    node_l1 <<<nodeGrid, 256, 0, stream>>>(x, W1, root1, b1, y, r1h);
    k_bhist <<<chunkGrid, 256, 0, stream>>>(ei, gcnt);
    k_bscan <<<1, 128, 0, stream>>>(gcnt, bucketBase, start);
    k_bucket<<<chunkGrid, 256, 0, stream>>>(ei, ea, bucketBase, gcursor, ebuf);
    k_bsort <<<NBUCKETS, 1024, 0, stream>>>(ebuf, bucketBase, es, start);
    k_agg1  <<<aggGrid, 256, 0, stream>>>(es, start, y, r1h);
    node_proj2<<<nodeGrid, 256, 0, stream>>>(r1h, W2, root2, b2, z, r2);
    k_agg2  <<<aggGrid, 256, 0, stream>>>(es, start, z, r2, out);
}